// Round 6
// baseline (273.481 us; speedup 1.0000x reference)
//
#include <hip/hip_runtime.h>
#include <hip/hip_bf16.h>

#define TT 512
#define II 46
#define HH 64
#define GG 192
#define CC 8
#define RR 8     // rows per block
#define KP 128   // fused K per gate: [h (64) | x (46, zero-padded to 64)]

typedef __attribute__((ext_vector_type(8))) _Float16 half8;
typedef __attribute__((ext_vector_type(4))) float float4v;

__device__ inline float fsigm(float xv) {
  return __builtin_amdgcn_rcpf(1.f + __expf(-xv));
}
// tanh(x) = 1 - 2/(1 + e^{2x}); saturates correctly at +-1, branch-free
__device__ inline float ftanh2(float xv) {
  float e = __expf(2.f * xv);
  return __builtin_fmaf(-2.f, __builtin_amdgcn_rcpf(1.f + e), 1.f);
}

// Barrier WITHOUT the vmcnt(0) drain __syncthreads would emit: LDS writes are
// made visible (lgkmcnt(0)); in-flight global x prefetches keep riding.
__device__ inline void barrier_lds_only() {
  asm volatile("s_waitcnt lgkmcnt(0)" ::: "memory");
  __builtin_amdgcn_s_barrier();
  asm volatile("" ::: "memory");
}

// wp[u][k] f16, u in [0,192): k<64 -> w_hh[u][k]; 64<=k<110 -> w_ih[u][k-64]; else 0.
__global__ void pack_w(const float* __restrict__ w_ih, const float* __restrict__ w_hh,
                       _Float16* __restrict__ wp) {
  int idx = blockIdx.x * 256 + threadIdx.x;  // 192*128 = 24576 exact
  int u = idx >> 7, k = idx & 127;
  float v = (k < HH) ? w_hh[u * HH + k]
                     : ((k < HH + II) ? w_ih[u * II + (k - HH)] : 0.f);
  wp[idx] = (_Float16)v;
}

// LDS frag layouts (f16): element (row m, k) lives at [k>>5][((k>>3)&3)*16 + m][k&7];
// lane l reads its A-frag for kstep s as frag[s][l][0..7].
// hsf: fused k 0..63 (h); xsf: fused k 64..127 (x, 46..63 zero).
__launch_bounds__(256, 1)
__global__ void gru_main(const float* __restrict__ x,
                         const float* __restrict__ b_ih, const float* __restrict__ b_hh,
                         const float* __restrict__ fc_w, const float* __restrict__ fc_b,
                         const _Float16* __restrict__ wp,
                         float* __restrict__ out) {
  __shared__ __align__(16) _Float16 hsf[2][2][64][8];
  __shared__ __align__(16) _Float16 xsf[2][2][64][8];
  __shared__ float hf[RR][HH + 1];
  __shared__ float fcw[CC * HH];
  __shared__ float fcbs[CC];
  __shared__ float lgts[RR][CC];

  const int tau = threadIdx.x;
  const int w4  = tau >> 6;   // wave 0..3 (units 16*w4 .. 16*w4+15)
  const int l   = tau & 63;
  const int m16 = l & 15;
  const int kg  = l >> 4;
  const int row0 = blockIdx.x * RR;

  {
    _Float16* p = &hsf[0][0][0][0];
    for (int i = tau; i < 2 * 2 * 64 * 8; i += 256) p[i] = (_Float16)0.f;
    p = &xsf[0][0][0][0];
    for (int i = tau; i < 2 * 2 * 64 * 8; i += 256) p[i] = (_Float16)0.f;
  }

  const int u = 16 * w4 + m16;   // gate unit (output col) owned by this lane
  const float br  = b_ih[u] + b_hh[u];
  const float bz  = b_ih[64 + u] + b_hh[64 + u];
  const float bnx = b_ih[128 + u];
  const float bnh = b_hh[128 + u];

  // persistent B-fragments: [gate r,z,n][kstep 0..3]
  half8 bf[3][4];
#pragma unroll
  for (int g = 0; g < 3; ++g) {
    const _Float16* bb = wp + (size_t)(64 * g + u) * KP + kg * 8;
#pragma unroll
    for (int s = 0; s < 4; ++s) bf[g][s] = *(const half8*)(bb + 32 * s);
  }

  // h write-back coords (unit u, rows row0l+i)
  const int sh  = w4 >> 1;
  const int kgp = (u >> 3) & 3;
  const int jp  = u & 7;
  const int row0l = (kg & 1) * 4 + (kg >> 1) * 2;  // kg0:{0,1} kg1:{4,5} kg2:{2,3} kg3:{6,7}
  const bool lo2 = (kg < 2);

  // x staging: thread owns elements tau and tau+256 of the 8x46 slab (368 total)
  const int r1 = tau / II, i1 = tau % II;
  const bool has2 = (tau + 256) < RR * II;
  const int e2 = tau + 256;
  const int r2 = has2 ? e2 / II : r1, i2 = has2 ? e2 % II : i1;
  const float* xp1 = x + (size_t)(row0 + r1) * TT * II + i1;
  const float* xp2 = x + (size_t)(row0 + r2) * TT * II + i2;
  const int s1 = i1 >> 5, kg1 = (i1 >> 3) & 3, j1 = i1 & 7;
  const int s2 = i2 >> 5, kg2 = (i2 >> 3) & 3, j2 = i2 & 7;

  auto stageX = [&](int buf, float va, float vb) {
    xsf[buf][s1][kg1 * 16 + r1][j1] = (_Float16)va;
    if (has2) xsf[buf][s2][kg2 * 16 + r2][j2] = (_Float16)vb;
  };

  float hreg[2] = {0.f, 0.f};

  // prologue: x(0) staged now; x(1) in xc (staged at t=0); x(2) in xn
  float v0a = xp1[0],       v0b = has2 ? xp2[0] : 0.f;
  float xc1 = xp1[II],      xc2 = has2 ? xp2[II] : 0.f;
  float xn1 = xp1[2 * II],  xn2 = has2 ? xp2[2 * II] : 0.f;
  __syncthreads();           // zero-init fence (outside loop: full sync fine)
  stageX(0, v0a, v0b);

  for (int t = 0; t < TT; ++t) {
    barrier_lds_only();      // hsf[cur]/xsf[cur] (written last iter) now visible
    const int cur = t & 1, nxt = cur ^ 1;
    half8 a0 = *(const half8*)&hsf[cur][0][l][0];
    half8 a1 = *(const half8*)&hsf[cur][1][l][0];
    half8 a2 = *(const half8*)&xsf[cur][0][l][0];
    half8 a3 = *(const half8*)&xsf[cur][1][l][0];

    // r,z: two independent 2-deep chains each, summed at the end.
    float4v r01 = {br, br, br, br};
    float4v r23 = {0.f, 0.f, 0.f, 0.f};
    float4v z01 = {bz, bz, bz, bz};
    float4v z23 = {0.f, 0.f, 0.f, 0.f};
    float4v accnh = {bnh, bnh, bnh, bnh};
    float4v accnx = {bnx, bnx, bnx, bnx};
    r01   = __builtin_amdgcn_mfma_f32_16x16x32_f16(a0, bf[0][0], r01, 0, 0, 0);
    r23   = __builtin_amdgcn_mfma_f32_16x16x32_f16(a2, bf[0][2], r23, 0, 0, 0);
    z01   = __builtin_amdgcn_mfma_f32_16x16x32_f16(a0, bf[1][0], z01, 0, 0, 0);
    z23   = __builtin_amdgcn_mfma_f32_16x16x32_f16(a2, bf[1][2], z23, 0, 0, 0);
    accnh = __builtin_amdgcn_mfma_f32_16x16x32_f16(a0, bf[2][0], accnh, 0, 0, 0);
    accnx = __builtin_amdgcn_mfma_f32_16x16x32_f16(a2, bf[2][2], accnx, 0, 0, 0);
    r01   = __builtin_amdgcn_mfma_f32_16x16x32_f16(a1, bf[0][1], r01, 0, 0, 0);
    r23   = __builtin_amdgcn_mfma_f32_16x16x32_f16(a3, bf[0][3], r23, 0, 0, 0);
    z01   = __builtin_amdgcn_mfma_f32_16x16x32_f16(a1, bf[1][1], z01, 0, 0, 0);
    z23   = __builtin_amdgcn_mfma_f32_16x16x32_f16(a3, bf[1][3], z23, 0, 0, 0);
    accnh = __builtin_amdgcn_mfma_f32_16x16x32_f16(a1, bf[2][1], accnh, 0, 0, 0);
    accnx = __builtin_amdgcn_mfma_f32_16x16x32_f16(a3, bf[2][3], accnx, 0, 0, 0);

    // staging + prefetch (global loads ride across barriers now)
    if (t + 1 < TT) stageX(nxt, xc1, xc2);
    xc1 = xn1; xc2 = xn2;
    if (t + 3 < TT) {
      xn1 = xp1[(size_t)(t + 3) * II];
      if (has2) xn2 = xp2[(size_t)(t + 3) * II];
    }

    float4v accr = r01 + r23;
    float4v accz = z01 + z23;

    // redistribute acc rows 2,3 (mod 4) across the xor-32 pair:
    // every lane ends with 2 real (row,unit) gate-sets.
    float r2s = __shfl_xor(accr[2], 32),  r3s = __shfl_xor(accr[3], 32);
    float z2s = __shfl_xor(accz[2], 32),  z3s = __shfl_xor(accz[3], 32);
    float h2s = __shfl_xor(accnh[2], 32), h3s = __shfl_xor(accnh[3], 32);
    float x2s = __shfl_xor(accnx[2], 32), x3s = __shfl_xor(accnx[3], 32);
    float aR[2]  = {lo2 ? accr[0]  : r2s, lo2 ? accr[1]  : r3s};
    float aZ[2]  = {lo2 ? accz[0]  : z2s, lo2 ? accz[1]  : z3s};
    float aNH[2] = {lo2 ? accnh[0] : h2s, lo2 ? accnh[1] : h3s};
    float aNX[2] = {lo2 ? accnx[0] : x2s, lo2 ? accnx[1] : x3s};

#pragma unroll
    for (int i = 0; i < 2; ++i) {
      float rg = fsigm(aR[i]);
      float zg = fsigm(aZ[i]);
      float pre = __builtin_fmaf(rg, aNH[i], aNX[i]);
      float ng = ftanh2(pre);
      hreg[i] = ng + zg * (hreg[i] - ng);
      hsf[nxt][sh][kgp * 16 + row0l + i][jp] = (_Float16)hreg[i];
    }
  }

  // ================= Epilogue: FC + softmax =================
  hf[row0l + 0][u] = hreg[0];
  hf[row0l + 1][u] = hreg[1];
  fcw[tau] = fc_w[tau];
  fcw[tau + 256] = fc_w[tau + 256];
  if (tau < CC) fcbs[tau] = fc_b[tau];
  __syncthreads();
  if (tau < RR * CC) {
    int rr = tau >> 3, c = tau & 7;
    float acc = fcbs[c];
#pragma unroll
    for (int j = 0; j < HH; ++j) acc += hf[rr][j] * fcw[c * HH + j];
    lgts[rr][c] = acc;
  }
  __syncthreads();
  if (tau < RR * CC) {
    int rr = tau >> 3, c = tau & 7;
    float mx = lgts[rr][0];
#pragma unroll
    for (int j = 1; j < CC; ++j) mx = fmaxf(mx, lgts[rr][j]);
    float ssum = 0.f;
#pragma unroll
    for (int j = 0; j < CC; ++j) ssum += __expf(lgts[rr][j] - mx);
    out[(size_t)(row0 + rr) * CC + c] = __expf(lgts[rr][c] - mx) / ssum;
  }
}

extern "C" void kernel_launch(void* const* d_in, const int* in_sizes, int n_in,
                              void* d_out, int out_size, void* d_ws, size_t ws_size,
                              hipStream_t stream) {
  const float* x    = (const float*)d_in[0];
  const float* w_ih = (const float*)d_in[1];
  const float* w_hh = (const float*)d_in[2];
  const float* b_ih = (const float*)d_in[3];
  const float* b_hh = (const float*)d_in[4];
  const float* fc_w = (const float*)d_in[5];
  const float* fc_b = (const float*)d_in[6];

  _Float16* wp = (_Float16*)d_ws;  // 192*128 f16 = 48 KiB

  pack_w<<<96, 256, 0, stream>>>(w_ih, w_hh, wp);
  gru_main<<<256, 256, 0, stream>>>(x, b_ih, b_hh, fc_w, fc_b, wp, (float*)d_out);
}

// Round 7
// 211.446 us; speedup vs baseline: 1.2934x; 1.2934x over previous
//
#include <hip/hip_runtime.h>
#include <hip/hip_bf16.h>

#define TT 512
#define II 46
#define HH 64
#define GG 192
#define CC 8
#define RR 8     // rows per block
#define KP 128   // fused K per gate: [h (64) | x (46, zero-padded to 64)]

typedef __attribute__((ext_vector_type(8))) _Float16 half8;
typedef __attribute__((ext_vector_type(4))) float float4v;

__device__ inline float fsigm(float xv) {
  return __builtin_amdgcn_rcpf(1.f + __expf(-xv));
}
// tanh(x) = 1 - 2/(1 + e^{2x}); saturates correctly at +-1, branch-free
__device__ inline float ftanh2(float xv) {
  float e = __expf(2.f * xv);
  return __builtin_fmaf(-2.f, __builtin_amdgcn_rcpf(1.f + e), 1.f);
}

// Barrier WITHOUT vmcnt drain: LDS ops fenced (lgkmcnt(0)); global x prefetches
// keep riding across (consumed 2 steps later).
__device__ inline void barrier_lds_only() {
  asm volatile("s_waitcnt lgkmcnt(0)" ::: "memory");
  __builtin_amdgcn_s_barrier();
  asm volatile("" ::: "memory");
}

// wp[u][k] f16, u in [0,192): k<64 -> w_hh[u][k]; 64<=k<110 -> w_ih[u][k-64]; else 0.
__global__ void pack_w(const float* __restrict__ w_ih, const float* __restrict__ w_hh,
                       _Float16* __restrict__ wp) {
  int idx = blockIdx.x * 256 + threadIdx.x;  // 192*128 = 24576 exact
  int u = idx >> 7, k = idx & 127;
  float v = (k < HH) ? w_hh[u * HH + k]
                     : ((k < HH + II) ? w_ih[u * II + (k - HH)] : 0.f);
  wp[idx] = (_Float16)v;
}

// Frag layout (f16): element (M-row m, k) at [k>>5][((k>>3)&3)*16 + m][k&7];
// lane l reads kstep s as frag[s][l][0..7] (m = l&15, k = 32s + (l>>4)*8 + j).
// Batch row b (0..7) lives at M-row mrow(b) = (b>>1)*4 + (b&1)  -> M rows
// {0,1,4,5,8,9,12,13}; every lane's acc elems e=0,1 (D rows kg*4+{0,1}) are the
// real batch rows {2kg, 2kg+1}. No post-MFMA shuffle needed. Other M rows stay 0.
// hsf: fused k 0..63 (h), double-buffered. xsf: x part (k-64 = i), TRIPLE-buffered
// so step t's x-fragments are readable during step t-1 (race-free via barriers).
__launch_bounds__(256, 1)
__global__ void gru_main(const float* __restrict__ x,
                         const float* __restrict__ b_ih, const float* __restrict__ b_hh,
                         const float* __restrict__ fc_w, const float* __restrict__ fc_b,
                         const _Float16* __restrict__ wp,
                         float* __restrict__ out) {
  __shared__ __align__(16) _Float16 hsf[2][2][64][8];
  __shared__ __align__(16) _Float16 xsf[3][2][64][8];
  __shared__ float hf[RR][HH + 1];
  __shared__ float fcw[CC * HH];
  __shared__ float fcbs[CC];
  __shared__ float lgts[RR][CC];

  const int tau = threadIdx.x;
  const int w4  = tau >> 6;   // wave 0..3 (units 16*w4 .. 16*w4+15)
  const int l   = tau & 63;
  const int m16 = l & 15;
  const int kg  = l >> 4;
  const int row0 = blockIdx.x * RR;

  {
    _Float16* p = &hsf[0][0][0][0];
    for (int i = tau; i < 2 * 2 * 64 * 8; i += 256) p[i] = (_Float16)0.f;
    p = &xsf[0][0][0][0];
    for (int i = tau; i < 3 * 2 * 64 * 8; i += 256) p[i] = (_Float16)0.f;
  }

  const int u = 16 * w4 + m16;   // gate unit (output col) owned by this lane
  const float br  = b_ih[u] + b_hh[u];
  const float bz  = b_ih[64 + u] + b_hh[64 + u];
  const float bnx = b_ih[128 + u];
  const float bnh = b_hh[128 + u];

  // persistent B-fragments: [gate r,z,n][kstep 0..3]; s=0,1 h-part, s=2,3 x-part
  half8 bf[3][4];
#pragma unroll
  for (int g = 0; g < 3; ++g) {
    const _Float16* bb = wp + (size_t)(64 * g + u) * KP + kg * 8;
#pragma unroll
    for (int s = 0; s < 4; ++s) bf[g][s] = *(const half8*)(bb + 32 * s);
  }

  // h write-back coords: h[b=2kg+i] at frag (m = 4kg+i, k = u)
  const int sh  = w4 >> 1;
  const int kgp = (u >> 3) & 3;
  const int jp  = u & 7;

  // x staging: thread owns elements tau and tau+256 of the 8x46 slab (368 total)
  const int r1 = tau / II, i1 = tau % II;
  const int m1 = (r1 >> 1) * 4 + (r1 & 1);
  const bool has2 = (tau + 256) < RR * II;
  const int e2 = tau + 256;
  const int r2 = has2 ? e2 / II : r1, i2 = has2 ? e2 % II : i1;
  const int m2 = (r2 >> 1) * 4 + (r2 & 1);
  const float* xp1 = x + (size_t)(row0 + r1) * TT * II + i1;
  const float* xp2 = x + (size_t)(row0 + r2) * TT * II + i2;
  const int s1 = i1 >> 5, kg1 = (i1 >> 3) & 3, j1 = i1 & 7;
  const int s2 = i2 >> 5, kg2 = (i2 >> 3) & 3, j2 = i2 & 7;

  auto stageX = [&](int buf, float va, float vb) {
    xsf[buf][s1][kg1 * 16 + m1][j1] = (_Float16)va;
    if (has2) xsf[buf][s2][kg2 * 16 + m2][j2] = (_Float16)vb;
  };

  float hreg[2] = {0.f, 0.f};

  // prologue: x(0)->buf0, x(1)->buf1; xc=x(2), xn=x(3)
  float v0a = xp1[0],            v0b = has2 ? xp2[0] : 0.f;
  float v1a = xp1[II],           v1b = has2 ? xp2[II] : 0.f;
  float xc1 = xp1[2 * II],       xc2 = has2 ? xp2[2 * II] : 0.f;
  float xn1 = xp1[3 * II],       xn2 = has2 ? xp2[3 * II] : 0.f;
  __syncthreads();               // zero-init fence
  stageX(0, v0a, v0b);
  stageX(1, v1a, v1b);
  __syncthreads();               // prologue staging fence

  // x-part pre-activations for t=0 (from buf0)
  float4v xr, xz, xnx;
  {
    half8 c0 = *(const half8*)&xsf[0][0][l][0];
    half8 c1 = *(const half8*)&xsf[0][1][l][0];
    float4v z4 = {0.f, 0.f, 0.f, 0.f};
    float4v bn4 = {bnx, bnx, bnx, bnx};
    xr  = __builtin_amdgcn_mfma_f32_16x16x32_f16(c0, bf[0][2], z4, 0, 0, 0);
    xr  = __builtin_amdgcn_mfma_f32_16x16x32_f16(c1, bf[0][3], xr, 0, 0, 0);
    xz  = __builtin_amdgcn_mfma_f32_16x16x32_f16(c0, bf[1][2], z4, 0, 0, 0);
    xz  = __builtin_amdgcn_mfma_f32_16x16x32_f16(c1, bf[1][3], xz, 0, 0, 0);
    xnx = __builtin_amdgcn_mfma_f32_16x16x32_f16(c0, bf[2][2], bn4, 0, 0, 0);
    xnx = __builtin_amdgcn_mfma_f32_16x16x32_f16(c1, bf[2][3], xnx, 0, 0, 0);
  }

  for (int t = 0; t < TT; ++t) {
    // stage x(t+2) into buf (t+2)%3 (pre-barrier; readers fenced by 2 barriers)
    if (t + 2 < TT) stageX((t + 2) % 3, xc1, xc2);
    xc1 = xn1; xc2 = xn2;
    if (t + 4 < TT) {
      xn1 = xp1[(size_t)(t + 4) * II];
      if (has2) xn2 = xp2[(size_t)(t + 4) * II];
    }

    barrier_lds_only();          // hsf[cur] (h(t)) now visible
    const int cur = t & 1, nxt = cur ^ 1;
    half8 a0 = *(const half8*)&hsf[cur][0][l][0];
    half8 a1 = *(const half8*)&hsf[cur][1][l][0];

    float4v r01 = {br, br, br, br};
    float4v z01 = {bz, bz, bz, bz};
    float4v nh  = {bnh, bnh, bnh, bnh};
    r01 = __builtin_amdgcn_mfma_f32_16x16x32_f16(a0, bf[0][0], r01, 0, 0, 0);
    nh  = __builtin_amdgcn_mfma_f32_16x16x32_f16(a0, bf[2][0], nh, 0, 0, 0);
    z01 = __builtin_amdgcn_mfma_f32_16x16x32_f16(a0, bf[1][0], z01, 0, 0, 0);
    r01 = __builtin_amdgcn_mfma_f32_16x16x32_f16(a1, bf[0][1], r01, 0, 0, 0);
    nh  = __builtin_amdgcn_mfma_f32_16x16x32_f16(a1, bf[2][1], nh, 0, 0, 0);
    z01 = __builtin_amdgcn_mfma_f32_16x16x32_f16(a1, bf[1][1], z01, 0, 0, 0);

    // combine with x-part (computed last step), only real elems e=0,1
    float aR[2]  = {r01[0] + xr[0], r01[1] + xr[1]};
    float aZ[2]  = {z01[0] + xz[0], z01[1] + xz[1]};
    float aNH[2] = {nh[0], nh[1]};
    float aNX[2] = {xnx[0], xnx[1]};

    // next step's x-part (independent of h -> fills dependency gaps)
    if (t + 1 < TT) {
      const int nb = (t + 1) % 3;
      half8 c0 = *(const half8*)&xsf[nb][0][l][0];
      half8 c1 = *(const half8*)&xsf[nb][1][l][0];
      float4v z4 = {0.f, 0.f, 0.f, 0.f};
      float4v bn4 = {bnx, bnx, bnx, bnx};
      xr  = __builtin_amdgcn_mfma_f32_16x16x32_f16(c0, bf[0][2], z4, 0, 0, 0);
      xr  = __builtin_amdgcn_mfma_f32_16x16x32_f16(c1, bf[0][3], xr, 0, 0, 0);
      xz  = __builtin_amdgcn_mfma_f32_16x16x32_f16(c0, bf[1][2], z4, 0, 0, 0);
      xz  = __builtin_amdgcn_mfma_f32_16x16x32_f16(c1, bf[1][3], xz, 0, 0, 0);
      xnx = __builtin_amdgcn_mfma_f32_16x16x32_f16(c0, bf[2][2], bn4, 0, 0, 0);
      xnx = __builtin_amdgcn_mfma_f32_16x16x32_f16(c1, bf[2][3], xnx, 0, 0, 0);
    }

#pragma unroll
    for (int i = 0; i < 2; ++i) {
      float rg = fsigm(aR[i]);
      float zg = fsigm(aZ[i]);
      float pre = __builtin_fmaf(rg, aNH[i], aNX[i]);
      float ng = ftanh2(pre);
      hreg[i] = __builtin_fmaf(zg, hreg[i] - ng, ng);
      hsf[nxt][sh][kgp * 16 + kg * 4 + i][jp] = (_Float16)hreg[i];
    }
  }

  // ================= Epilogue: FC + softmax =================
  hf[2 * kg + 0][u] = hreg[0];
  hf[2 * kg + 1][u] = hreg[1];
  fcw[tau] = fc_w[tau];
  fcw[tau + 256] = fc_w[tau + 256];
  if (tau < CC) fcbs[tau] = fc_b[tau];
  __syncthreads();
  if (tau < RR * CC) {
    int rr = tau >> 3, c = tau & 7;
    float acc = fcbs[c];
#pragma unroll
    for (int j = 0; j < HH; ++j) acc += hf[rr][j] * fcw[c * HH + j];
    lgts[rr][c] = acc;
  }
  __syncthreads();
  if (tau < RR * CC) {
    int rr = tau >> 3, c = tau & 7;
    float mx = lgts[rr][0];
#pragma unroll
    for (int j = 1; j < CC; ++j) mx = fmaxf(mx, lgts[rr][j]);
    float ssum = 0.f;
#pragma unroll
    for (int j = 0; j < CC; ++j) ssum += __expf(lgts[rr][j] - mx);
    out[(size_t)(row0 + rr) * CC + c] = __expf(lgts[rr][c] - mx) / ssum;
  }
}

extern "C" void kernel_launch(void* const* d_in, const int* in_sizes, int n_in,
                              void* d_out, int out_size, void* d_ws, size_t ws_size,
                              hipStream_t stream) {
  const float* x    = (const float*)d_in[0];
  const float* w_ih = (const float*)d_in[1];
  const float* w_hh = (const float*)d_in[2];
  const float* b_ih = (const float*)d_in[3];
  const float* b_hh = (const float*)d_in[4];
  const float* fc_w = (const float*)d_in[5];
  const float* fc_b = (const float*)d_in[6];

  _Float16* wp = (_Float16*)d_ws;  // 192*128 f16 = 48 KiB

  pack_w<<<96, 256, 0, stream>>>(w_ih, w_hh, wp);
  gru_main<<<256, 256, 0, stream>>>(x, b_ih, b_hh, fc_w, fc_b, wp, (float*)d_out);
}